// Round 4
// baseline (1061.507 us; speedup 1.0000x reference)
//
#include <hip/hip_runtime.h>

#define B_TOT 131072
#define L_ 9
#define D_ 22
#define H_ 2
#define FF_ 128
#define RPB 28            // rows per block
#define TPB (RPB * L_)    // 252 threads

// ---- workspace layout (floats) ----
#define WS_PE    0      // pe[9][22]                                  : 198
#define WS_PB    198    // pbias[h][i][j]                             : 162
#define WS_MT    360    // MT[h][d][c]  = (Wq_h Wk_h^T/sqrt22)[c][d]  : 968
#define WS_VWO   1328   // WVOT[h][d][c]= (Wv_h Wo_h)[c][d]           : 968
#define WS_W1T   2296   // W1T[f][c]    = W1[c][f]                    : 2816
#define WS_WRES  5112   // W_res'[c] = g_ff[c]*W_res[c]               : 22
#define WS_BRES  5134   // [0]=b_res + b_ff@W_res, [1]=sum(W_res')    : 2
// total 5136 floats = 20544 bytes

__global__ void setup_k(const float* __restrict__ W_rel, const float* __restrict__ b_rel,
                        const float* __restrict__ Wq, const float* __restrict__ Wk,
                        const float* __restrict__ Wv, const float* __restrict__ Wo,
                        const float* __restrict__ W1, const float* __restrict__ Wp,
                        const float* __restrict__ bp, const float* __restrict__ g_ff,
                        const float* __restrict__ b_ff, const float* __restrict__ W_res,
                        const float* __restrict__ b_res, float* __restrict__ ws)
{
    const int t = threadIdx.x;
    for (int idx = t; idx < 198; idx += 256) {
        int l = idx / 22, d = idx % 22, tt = d / 2;
        float div = __expf((float)(2 * tt) * (-logf(10000.f) / 22.f));
        float ang = (float)l * div;
        ws[WS_PE + idx] = (d & 1) ? cosf(ang) : sinf(ang);
    }
    for (int idx = t; idx < 162; idx += 256) {
        int h = idx / 81, rem = idx % 81, i = rem / 9, j = rem % 9;
        float s = bp[h];
        for (int d = 0; d < 22; ++d)
            s += (W_rel[(i - j + 9) * 22 + d] + b_rel[d]) * Wp[d * 2 + h];
        ws[WS_PB + idx] = s;
    }
    for (int idx = t; idx < 968; idx += 256) {
        int h = idx / 484, rem = idx % 484, cp = rem / 22, c = rem % 22;
        float s = 0.f;
        for (int e = 0; e < 22; ++e)
            s += Wq[c * 44 + h * 22 + e] * Wk[cp * 44 + h * 22 + e];
        ws[WS_MT + idx] = s * 0.21320071635561041f; // 1/sqrt(22)
    }
    for (int idx = t; idx < 968; idx += 256) {
        int h = idx / 484, rem = idx % 484, d = rem / 22, c = rem % 22;
        float s = 0.f;
        for (int e = 0; e < 22; ++e)
            s += Wv[c * 44 + h * 22 + e] * Wo[(h * 22 + e) * 22 + d];
        ws[WS_VWO + idx] = s;
    }
    for (int idx = t; idx < 2816; idx += 256) {
        int f = idx / 22, c = idx % 22;
        ws[WS_W1T + idx] = W1[c * 128 + f];
    }
    // folded residue head: W_res' = g_ff .* W_res ; b_res' = b_res + b_ff@W_res ; SW = sum(W_res')
    if (t < 22) ws[WS_WRES + t] = g_ff[t] * W_res[t];
    if (t == 0) {
        float br = b_res[0], sw = 0.f;
        for (int c = 0; c < 22; ++c) {
            br += b_ff[c] * W_res[c];
            sw += g_ff[c] * W_res[c];
        }
        ws[WS_BRES + 0] = br;
        ws[WS_BRES + 1] = sw;
    }
}

__global__ __launch_bounds__(TPB, 4) void fused_model(
    const float* __restrict__ seq, const float* __restrict__ ws,
    const float* __restrict__ g_att, const float* __restrict__ b_att,
    const float* __restrict__ b1, const float* __restrict__ W2,
    const float* __restrict__ b2, const float* __restrict__ W_out,
    const float* __restrict__ b_out, float* __restrict__ out)
{
    // x rows (padded to 24); x stays valid through the whole attention phase.
    __shared__ __align__(16) float xbuf[RPB][L_][24];   // 24192 B

    const int tid = threadIdx.x;
    const int r = tid / L_;
    const int i = tid - r * L_;
    const long g = (long)blockIdx.x * RPB + r;
    const bool active = g < B_TOT;
    const long gc = active ? g : (long)(B_TOT - 1);

    // ---- prefetch attention bias into the score accumulators ----
    float p0[L_], p1[L_];
    {
        const float* pb = ws + WS_PB + i * L_;
        #pragma unroll
        for (int j = 0; j < L_; ++j) p0[j] = pb[j];
        #pragma unroll
        for (int j = 0; j < L_; ++j) p1[j] = pb[81 + j];
    }

    // ---- load x = seq_embd + pe ----
    float x[D_];
    {
        const float* xin = seq + gc * (L_ * D_) + i * D_;
        const float* pe  = ws + WS_PE + i * D_;
        #pragma unroll
        for (int c = 0; c < D_; c += 2) {
            float2 t = *reinterpret_cast<const float2*>(xin + c);
            x[c]     = t.x + pe[c];
            x[c + 1] = t.y + pe[c + 1];
        }
    }
    {
        float4* row = reinterpret_cast<float4*>(&xbuf[r][i][0]);
        row[0] = make_float4(x[0], x[1], x[2], x[3]);
        row[1] = make_float4(x[4], x[5], x[6], x[7]);
        row[2] = make_float4(x[8], x[9], x[10], x[11]);
        row[3] = make_float4(x[12], x[13], x[14], x[15]);
        row[4] = make_float4(x[16], x[17], x[18], x[19]);
        row[5] = make_float4(x[20], x[21], 0.f, 0.f);
    }
    __syncthreads();   // the ONLY data barrier in the attention phase

    // ---- scores for BOTH heads ----
    #pragma unroll
    for (int h = 0; h < H_; ++h) {
        const float* MT = ws + WS_MT + h * (D_ * D_);
        float qm[D_];
        #pragma unroll
        for (int d = 0; d < D_; ++d) {
            float s = 0.f;
            #pragma unroll
            for (int c = 0; c < D_; ++c) s += x[c] * MT[d * D_ + c];
            qm[d] = s;
        }
        float* p = h ? p1 : p0;
        #pragma unroll
        for (int j = 0; j < L_; ++j) {
            const float4* xr = reinterpret_cast<const float4*>(&xbuf[r][j][0]);
            float4 a0 = xr[0], a1 = xr[1], a2 = xr[2], a3 = xr[3], a4 = xr[4];
            float2 a5 = *reinterpret_cast<const float2*>(&xbuf[r][j][20]);
            float s = p[j];
            s += qm[0]*a0.x + qm[1]*a0.y + qm[2]*a0.z + qm[3]*a0.w;
            s += qm[4]*a1.x + qm[5]*a1.y + qm[6]*a1.z + qm[7]*a1.w;
            s += qm[8]*a2.x + qm[9]*a2.y + qm[10]*a2.z + qm[11]*a2.w;
            s += qm[12]*a3.x + qm[13]*a3.y + qm[14]*a3.z + qm[15]*a3.w;
            s += qm[16]*a4.x + qm[17]*a4.y + qm[18]*a4.z + qm[19]*a4.w;
            s += qm[20]*a5.x + qm[21]*a5.y;
            p[j] = s;
        }
    }

    // ---- softmax both heads, in registers (pre-normalized) ----
    {
        float mx = -1e30f;
        #pragma unroll
        for (int j = 0; j < L_; ++j) mx = fmaxf(mx, p0[j]);
        float sum = 0.f;
        #pragma unroll
        for (int j = 0; j < L_; ++j) { p0[j] = __expf(p0[j] - mx); sum += p0[j]; }
        const float inv = 1.f / sum;
        #pragma unroll
        for (int j = 0; j < L_; ++j) p0[j] *= inv;
    }
    {
        float mx = -1e30f;
        #pragma unroll
        for (int j = 0; j < L_; ++j) mx = fmaxf(mx, p1[j]);
        float sum = 0.f;
        #pragma unroll
        for (int j = 0; j < L_; ++j) { p1[j] = __expf(p1[j] - mx); sum += p1[j]; }
        const float inv = 1.f / sum;
        #pragma unroll
        for (int j = 0; j < L_; ++j) p1[j] *= inv;
    }

    // ---- att = sum_h (sum_j p_hj x_j) @ Wvo_h  (ctx first, then project) ----
    float att[D_];
    #pragma unroll
    for (int c = 0; c < D_; ++c) att[c] = 0.f;

    #pragma unroll
    for (int h = 0; h < H_; ++h) {
        const float* WVOT = ws + WS_VWO + h * (D_ * D_);
        const float* p = h ? p1 : p0;
        float ctx[D_];
        #pragma unroll
        for (int c = 0; c < D_; ++c) ctx[c] = 0.f;
        #pragma unroll
        for (int j = 0; j < L_; ++j) {
            const float4* xr = reinterpret_cast<const float4*>(&xbuf[r][j][0]);
            float4 a0 = xr[0], a1 = xr[1], a2 = xr[2], a3 = xr[3], a4 = xr[4];
            float2 a5 = *reinterpret_cast<const float2*>(&xbuf[r][j][20]);
            const float pj = p[j];
            ctx[0]  += pj * a0.x; ctx[1]  += pj * a0.y; ctx[2]  += pj * a0.z; ctx[3]  += pj * a0.w;
            ctx[4]  += pj * a1.x; ctx[5]  += pj * a1.y; ctx[6]  += pj * a1.z; ctx[7]  += pj * a1.w;
            ctx[8]  += pj * a2.x; ctx[9]  += pj * a2.y; ctx[10] += pj * a2.z; ctx[11] += pj * a2.w;
            ctx[12] += pj * a3.x; ctx[13] += pj * a3.y; ctx[14] += pj * a3.z; ctx[15] += pj * a3.w;
            ctx[16] += pj * a4.x; ctx[17] += pj * a4.y; ctx[18] += pj * a4.z; ctx[19] += pj * a4.w;
            ctx[20] += pj * a5.x; ctx[21] += pj * a5.y;
        }
        #pragma unroll
        for (int d = 0; d < D_; ++d) {
            float s = 0.f;
            #pragma unroll
            for (int c = 0; c < D_; ++c) s += ctx[c] * WVOT[d * D_ + c];
            att[d] += s;
        }
    }

    // ---- LayerNorm 1 (residual) ----
    {
        float s = 0.f;
        #pragma unroll
        for (int c = 0; c < D_; ++c) { x[c] += att[c]; s += x[c]; }
        const float mean = s * (1.f / 22.f);
        float vs = 0.f;
        #pragma unroll
        for (int c = 0; c < D_; ++c) { float d = x[c] - mean; vs += d * d; }
        const float rstd = rsqrtf(vs * (1.f / 22.f) + 1e-5f);
        #pragma unroll
        for (int c = 0; c < D_; ++c) x[c] = (x[c] - mean) * rstd * g_att[c] + b_att[c];
    }

    // ---- feed-forward (residual into x) ----
    {
        float y2[D_];
        #pragma unroll
        for (int c = 0; c < D_; ++c) y2[c] = b2[c];
        const float* W1T = ws + WS_W1T;
        #pragma unroll 4
        for (int f = 0; f < FF_; ++f) {
            float s = b1[f];
            #pragma unroll
            for (int c = 0; c < D_; ++c) s += x[c] * W1T[f * D_ + c];
            s = fmaxf(s, 0.f);
            #pragma unroll
            for (int c = 0; c < D_; ++c) y2[c] += s * W2[f * D_ + c];
        }
        #pragma unroll
        for (int c = 0; c < D_; ++c) x[c] += y2[c];
    }

    // ---- LN2 + residue head, fully folded:
    //      pr = b_res' + rstd * (dot(t, W_res') - mean * sum(W_res'))   ----
    float pr;
    {
        float s = 0.f;
        #pragma unroll
        for (int c = 0; c < D_; ++c) s += x[c];
        const float mean = s * (1.f / 22.f);
        float vs = 0.f;
        #pragma unroll
        for (int c = 0; c < D_; ++c) { float d = x[c] - mean; vs += d * d; }
        const float rstd = rsqrtf(vs * (1.f / 22.f) + 1e-5f);
        const float* wr = ws + WS_WRES;
        float dot = 0.f;
        #pragma unroll
        for (int c = 0; c < D_; ++c) dot += x[c] * wr[c];
        pr = ws[WS_BRES + 0] + rstd * (dot - mean * ws[WS_BRES + 1]);
    }

    // ---- output head (reduce over L via LDS overlay) ----
    float* red = reinterpret_cast<float*>(xbuf);   // overlay: [tid*2 + {0,1}]
    __syncthreads();   // all xbuf reads done before overlay write
    red[tid * 2 + 0] = pr * W_out[i * 2 + 0];
    red[tid * 2 + 1] = pr * W_out[i * 2 + 1];
    __syncthreads();
    if (i == 0 && active) {
        float o0 = b_out[0], o1 = b_out[1];
        #pragma unroll
        for (int j = 0; j < L_; ++j) {
            o0 += red[(r * L_ + j) * 2 + 0];
            o1 += red[(r * L_ + j) * 2 + 1];
        }
        float2 o; o.x = o0; o.y = o1;
        *reinterpret_cast<float2*>(out + g * 2) = o;
    }
}

extern "C" void kernel_launch(void* const* d_in, const int* in_sizes, int n_in,
                              void* d_out, int out_size, void* d_ws, size_t ws_size,
                              hipStream_t stream)
{
    const float* seq   = (const float*)d_in[0];
    const float* W_rel = (const float*)d_in[1];
    const float* b_rel = (const float*)d_in[2];
    const float* Wq    = (const float*)d_in[3];
    const float* Wk    = (const float*)d_in[4];
    const float* Wv    = (const float*)d_in[5];
    const float* Wo    = (const float*)d_in[6];
    const float* g_att = (const float*)d_in[7];
    const float* b_att = (const float*)d_in[8];
    const float* W1    = (const float*)d_in[9];
    const float* b1    = (const float*)d_in[10];
    const float* W2    = (const float*)d_in[11];
    const float* b2    = (const float*)d_in[12];
    const float* Wp    = (const float*)d_in[13];
    const float* bp    = (const float*)d_in[14];
    const float* g_ff  = (const float*)d_in[15];
    const float* b_ff  = (const float*)d_in[16];
    const float* W_res = (const float*)d_in[17];
    const float* b_res = (const float*)d_in[18];
    const float* W_out = (const float*)d_in[19];
    const float* b_out = (const float*)d_in[20];
    float* out = (float*)d_out;
    float* ws  = (float*)d_ws;

    setup_k<<<1, 256, 0, stream>>>(W_rel, b_rel, Wq, Wk, Wv, Wo, W1, Wp, bp,
                                   g_ff, b_ff, W_res, b_res, ws);

    const int grid = (B_TOT + RPB - 1) / RPB;
    fused_model<<<grid, TPB, 0, stream>>>(seq, ws, g_att, b_att, b1, W2, b2,
                                          W_out, b_out, out);
}

// Round 5
// 1047.274 us; speedup vs baseline: 1.0136x; 1.0136x over previous
//
#include <hip/hip_runtime.h>

#define B_TOT 131072
#define L_ 9
#define D_ 22
#define H_ 2
#define FF_ 128
#define RPB 28            // rows per block
#define TPB (RPB * L_)    // 252 threads

// ---- workspace layout (floats) ----
#define WS_PE    0      // pe[9][22]                                  : 198
#define WS_PB    198    // pbias[h][i][j]                             : 162
#define WS_MT    360    // MT[h][d][c]  = (Wq_h Wk_h^T/sqrt22)[c][d]  : 968
#define WS_VWO   1328   // WVOT[h][d][c]= (Wv_h Wo_h)[c][d]           : 968
#define WS_W1T   2296   // W1T[f][c]    = W1[c][f]                    : 2816
#define WS_WRES  5112   // W_res'[c] = g_ff[c]*W_res[c]               : 22
#define WS_BRES  5134   // [0]=b_res + b_ff@W_res, [1]=sum(W_res')    : 2
// total 5136 floats = 20544 bytes

__global__ void setup_k(const float* __restrict__ W_rel, const float* __restrict__ b_rel,
                        const float* __restrict__ Wq, const float* __restrict__ Wk,
                        const float* __restrict__ Wv, const float* __restrict__ Wo,
                        const float* __restrict__ W1, const float* __restrict__ Wp,
                        const float* __restrict__ bp, const float* __restrict__ g_ff,
                        const float* __restrict__ b_ff, const float* __restrict__ W_res,
                        const float* __restrict__ b_res, float* __restrict__ ws)
{
    const int t = threadIdx.x;
    for (int idx = t; idx < 198; idx += 256) {
        int l = idx / 22, d = idx % 22, tt = d / 2;
        float div = __expf((float)(2 * tt) * (-logf(10000.f) / 22.f));
        float ang = (float)l * div;
        ws[WS_PE + idx] = (d & 1) ? cosf(ang) : sinf(ang);
    }
    for (int idx = t; idx < 162; idx += 256) {
        int h = idx / 81, rem = idx % 81, i = rem / 9, j = rem % 9;
        float s = bp[h];
        for (int d = 0; d < 22; ++d)
            s += (W_rel[(i - j + 9) * 22 + d] + b_rel[d]) * Wp[d * 2 + h];
        ws[WS_PB + idx] = s;
    }
    for (int idx = t; idx < 968; idx += 256) {
        int h = idx / 484, rem = idx % 484, cp = rem / 22, c = rem % 22;
        float s = 0.f;
        for (int e = 0; e < 22; ++e)
            s += Wq[c * 44 + h * 22 + e] * Wk[cp * 44 + h * 22 + e];
        ws[WS_MT + idx] = s * 0.21320071635561041f; // 1/sqrt(22)
    }
    for (int idx = t; idx < 968; idx += 256) {
        int h = idx / 484, rem = idx % 484, d = rem / 22, c = rem % 22;
        float s = 0.f;
        for (int e = 0; e < 22; ++e)
            s += Wv[c * 44 + h * 22 + e] * Wo[(h * 22 + e) * 22 + d];
        ws[WS_VWO + idx] = s;
    }
    for (int idx = t; idx < 2816; idx += 256) {
        int f = idx / 22, c = idx % 22;
        ws[WS_W1T + idx] = W1[c * 128 + f];
    }
    // folded residue head: W_res' = g_ff .* W_res ; b_res' = b_res + b_ff@W_res ; SW = sum(W_res')
    if (t < 22) ws[WS_WRES + t] = g_ff[t] * W_res[t];
    if (t == 0) {
        float br = b_res[0], sw = 0.f;
        for (int c = 0; c < 22; ++c) {
            br += b_ff[c] * W_res[c];
            sw += g_ff[c] * W_res[c];
        }
        ws[WS_BRES + 0] = br;
        ws[WS_BRES + 1] = sw;
    }
}

// NOTE: no min-waves-per-EU arg — hipcc budgets it against a 256-reg pool
// (N=4 -> 64-reg cap -> catastrophic spill, rounds 2/4). Unconstrained, the
// allocator picks ~96-128 regs; occupancy step at VGPR<=128 gives 16 waves/CU.
__global__ __launch_bounds__(TPB) void fused_model(
    const float* __restrict__ seq, const float* __restrict__ ws,
    const float* __restrict__ g_att, const float* __restrict__ b_att,
    const float* __restrict__ b1, const float* __restrict__ W2,
    const float* __restrict__ b2, const float* __restrict__ W_out,
    const float* __restrict__ b_out, float* __restrict__ out)
{
    // x rows (padded to 24); x stays valid through the whole attention phase.
    __shared__ __align__(16) float xbuf[RPB][L_][24];   // 24192 B

    const int tid = threadIdx.x;
    const int r = tid / L_;
    const int i = tid - r * L_;
    const long g = (long)blockIdx.x * RPB + r;
    const bool active = g < B_TOT;
    const long gc = active ? g : (long)(B_TOT - 1);

    // ---- prefetch attention bias into the score accumulators ----
    float p0[L_], p1[L_];
    {
        const float* pb = ws + WS_PB + i * L_;
        #pragma unroll
        for (int j = 0; j < L_; ++j) p0[j] = pb[j];
        #pragma unroll
        for (int j = 0; j < L_; ++j) p1[j] = pb[81 + j];
    }

    // ---- load x = seq_embd + pe ----
    float x[D_];
    {
        const float* xin = seq + gc * (L_ * D_) + i * D_;
        const float* pe  = ws + WS_PE + i * D_;
        #pragma unroll
        for (int c = 0; c < D_; c += 2) {
            float2 t = *reinterpret_cast<const float2*>(xin + c);
            x[c]     = t.x + pe[c];
            x[c + 1] = t.y + pe[c + 1];
        }
    }
    {
        float4* row = reinterpret_cast<float4*>(&xbuf[r][i][0]);
        row[0] = make_float4(x[0], x[1], x[2], x[3]);
        row[1] = make_float4(x[4], x[5], x[6], x[7]);
        row[2] = make_float4(x[8], x[9], x[10], x[11]);
        row[3] = make_float4(x[12], x[13], x[14], x[15]);
        row[4] = make_float4(x[16], x[17], x[18], x[19]);
        row[5] = make_float4(x[20], x[21], 0.f, 0.f);
    }
    __syncthreads();   // the ONLY data barrier in the attention phase

    // ---- scores for BOTH heads ----
    #pragma unroll
    for (int h = 0; h < H_; ++h) {
        const float* MT = ws + WS_MT + h * (D_ * D_);
        float qm[D_];
        #pragma unroll
        for (int d = 0; d < D_; ++d) {
            float s = 0.f;
            #pragma unroll
            for (int c = 0; c < D_; ++c) s += x[c] * MT[d * D_ + c];
            qm[d] = s;
        }
        float* p = h ? p1 : p0;
        #pragma unroll
        for (int j = 0; j < L_; ++j) {
            const float4* xr = reinterpret_cast<const float4*>(&xbuf[r][j][0]);
            float4 a0 = xr[0], a1 = xr[1], a2 = xr[2], a3 = xr[3], a4 = xr[4];
            float2 a5 = *reinterpret_cast<const float2*>(&xbuf[r][j][20]);
            float s = p[j];
            s += qm[0]*a0.x + qm[1]*a0.y + qm[2]*a0.z + qm[3]*a0.w;
            s += qm[4]*a1.x + qm[5]*a1.y + qm[6]*a1.z + qm[7]*a1.w;
            s += qm[8]*a2.x + qm[9]*a2.y + qm[10]*a2.z + qm[11]*a2.w;
            s += qm[12]*a3.x + qm[13]*a3.y + qm[14]*a3.z + qm[15]*a3.w;
            s += qm[16]*a4.x + qm[17]*a4.y + qm[18]*a4.z + qm[19]*a4.w;
            s += qm[20]*a5.x + qm[21]*a5.y;
            p[j] = s;
        }
    }

    // ---- softmax both heads, in registers (pre-normalized) ----
    {
        float mx = -1e30f;
        #pragma unroll
        for (int j = 0; j < L_; ++j) mx = fmaxf(mx, p0[j]);
        float sum = 0.f;
        #pragma unroll
        for (int j = 0; j < L_; ++j) { p0[j] = __expf(p0[j] - mx); sum += p0[j]; }
        const float inv = 1.f / sum;
        #pragma unroll
        for (int j = 0; j < L_; ++j) p0[j] *= inv;
    }
    {
        float mx = -1e30f;
        #pragma unroll
        for (int j = 0; j < L_; ++j) mx = fmaxf(mx, p1[j]);
        float sum = 0.f;
        #pragma unroll
        for (int j = 0; j < L_; ++j) { p1[j] = __expf(p1[j] - mx); sum += p1[j]; }
        const float inv = 1.f / sum;
        #pragma unroll
        for (int j = 0; j < L_; ++j) p1[j] *= inv;
    }

    // ---- att = sum_h (sum_j p_hj x_j) @ Wvo_h  (ctx first, then project) ----
    float att[D_];
    #pragma unroll
    for (int c = 0; c < D_; ++c) att[c] = 0.f;

    #pragma unroll
    for (int h = 0; h < H_; ++h) {
        const float* WVOT = ws + WS_VWO + h * (D_ * D_);
        const float* p = h ? p1 : p0;
        float ctx[D_];
        #pragma unroll
        for (int c = 0; c < D_; ++c) ctx[c] = 0.f;
        #pragma unroll
        for (int j = 0; j < L_; ++j) {
            const float4* xr = reinterpret_cast<const float4*>(&xbuf[r][j][0]);
            float4 a0 = xr[0], a1 = xr[1], a2 = xr[2], a3 = xr[3], a4 = xr[4];
            float2 a5 = *reinterpret_cast<const float2*>(&xbuf[r][j][20]);
            const float pj = p[j];
            ctx[0]  += pj * a0.x; ctx[1]  += pj * a0.y; ctx[2]  += pj * a0.z; ctx[3]  += pj * a0.w;
            ctx[4]  += pj * a1.x; ctx[5]  += pj * a1.y; ctx[6]  += pj * a1.z; ctx[7]  += pj * a1.w;
            ctx[8]  += pj * a2.x; ctx[9]  += pj * a2.y; ctx[10] += pj * a2.z; ctx[11] += pj * a2.w;
            ctx[12] += pj * a3.x; ctx[13] += pj * a3.y; ctx[14] += pj * a3.z; ctx[15] += pj * a3.w;
            ctx[16] += pj * a4.x; ctx[17] += pj * a4.y; ctx[18] += pj * a4.z; ctx[19] += pj * a4.w;
            ctx[20] += pj * a5.x; ctx[21] += pj * a5.y;
        }
        #pragma unroll
        for (int d = 0; d < D_; ++d) {
            float s = 0.f;
            #pragma unroll
            for (int c = 0; c < D_; ++c) s += ctx[c] * WVOT[d * D_ + c];
            att[d] += s;
        }
    }

    // ---- LayerNorm 1 (residual) ----
    {
        float s = 0.f;
        #pragma unroll
        for (int c = 0; c < D_; ++c) { x[c] += att[c]; s += x[c]; }
        const float mean = s * (1.f / 22.f);
        float vs = 0.f;
        #pragma unroll
        for (int c = 0; c < D_; ++c) { float d = x[c] - mean; vs += d * d; }
        const float rstd = rsqrtf(vs * (1.f / 22.f) + 1e-5f);
        #pragma unroll
        for (int c = 0; c < D_; ++c) x[c] = (x[c] - mean) * rstd * g_att[c] + b_att[c];
    }

    // ---- feed-forward (residual into x) ----
    {
        float y2[D_];
        #pragma unroll
        for (int c = 0; c < D_; ++c) y2[c] = b2[c];
        const float* W1T = ws + WS_W1T;
        #pragma unroll 4
        for (int f = 0; f < FF_; ++f) {
            float s = b1[f];
            #pragma unroll
            for (int c = 0; c < D_; ++c) s += x[c] * W1T[f * D_ + c];
            s = fmaxf(s, 0.f);
            #pragma unroll
            for (int c = 0; c < D_; ++c) y2[c] += s * W2[f * D_ + c];
        }
        #pragma unroll
        for (int c = 0; c < D_; ++c) x[c] += y2[c];
    }

    // ---- LN2 + residue head, fully folded:
    //      pr = b_res' + rstd * (dot(t, W_res') - mean * sum(W_res'))   ----
    float pr;
    {
        float s = 0.f;
        #pragma unroll
        for (int c = 0; c < D_; ++c) s += x[c];
        const float mean = s * (1.f / 22.f);
        float vs = 0.f;
        #pragma unroll
        for (int c = 0; c < D_; ++c) { float d = x[c] - mean; vs += d * d; }
        const float rstd = rsqrtf(vs * (1.f / 22.f) + 1e-5f);
        const float* wr = ws + WS_WRES;
        float dot = 0.f;
        #pragma unroll
        for (int c = 0; c < D_; ++c) dot += x[c] * wr[c];
        pr = ws[WS_BRES + 0] + rstd * (dot - mean * ws[WS_BRES + 1]);
    }

    // ---- output head (reduce over L via LDS overlay) ----
    float* red = reinterpret_cast<float*>(xbuf);   // overlay: [tid*2 + {0,1}]
    __syncthreads();   // all xbuf reads done before overlay write
    red[tid * 2 + 0] = pr * W_out[i * 2 + 0];
    red[tid * 2 + 1] = pr * W_out[i * 2 + 1];
    __syncthreads();
    if (i == 0 && active) {
        float o0 = b_out[0], o1 = b_out[1];
        #pragma unroll
        for (int j = 0; j < L_; ++j) {
            o0 += red[(r * L_ + j) * 2 + 0];
            o1 += red[(r * L_ + j) * 2 + 1];
        }
        float2 o; o.x = o0; o.y = o1;
        *reinterpret_cast<float2*>(out + g * 2) = o;
    }
}

extern "C" void kernel_launch(void* const* d_in, const int* in_sizes, int n_in,
                              void* d_out, int out_size, void* d_ws, size_t ws_size,
                              hipStream_t stream)
{
    const float* seq   = (const float*)d_in[0];
    const float* W_rel = (const float*)d_in[1];
    const float* b_rel = (const float*)d_in[2];
    const float* Wq    = (const float*)d_in[3];
    const float* Wk    = (const float*)d_in[4];
    const float* Wv    = (const float*)d_in[5];
    const float* Wo    = (const float*)d_in[6];
    const float* g_att = (const float*)d_in[7];
    const float* b_att = (const float*)d_in[8];
    const float* W1    = (const float*)d_in[9];
    const float* b1    = (const float*)d_in[10];
    const float* W2    = (const float*)d_in[11];
    const float* b2    = (const float*)d_in[12];
    const float* Wp    = (const float*)d_in[13];
    const float* bp    = (const float*)d_in[14];
    const float* g_ff  = (const float*)d_in[15];
    const float* b_ff  = (const float*)d_in[16];
    const float* W_res = (const float*)d_in[17];
    const float* b_res = (const float*)d_in[18];
    const float* W_out = (const float*)d_in[19];
    const float* b_out = (const float*)d_in[20];
    float* out = (float*)d_out;
    float* ws  = (float*)d_ws;

    setup_k<<<1, 256, 0, stream>>>(W_rel, b_rel, Wq, Wk, Wv, Wo, W1, Wp, bp,
                                   g_ff, b_ff, W_res, b_res, ws);

    const int grid = (B_TOT + RPB - 1) / RPB;
    fused_model<<<grid, TPB, 0, stream>>>(seq, ws, g_att, b_att, b1, W2, b2,
                                          W_out, b_out, out);
}

// Round 7
// 875.550 us; speedup vs baseline: 1.2124x; 1.1961x over previous
//
#include <hip/hip_runtime.h>

#define B_TOT 131072
#define L_ 9
#define D_ 22
#define H_ 2
#define FF_ 128
#define RPB 28            // rows per block
#define TPB (RPB * L_)    // 252 threads

// ---- workspace layout (floats) ----
#define WS_PE    0      // pe[9][22]                                  : 198
#define WS_PB    198    // pbias[h][i][j]                             : 162
#define WS_MT    360    // MT[h][d][c]  = (Wq_h Wk_h^T/sqrt22)[c][d]  : 968
#define WS_VWO   1328   // WVOT[h][d][c]= (Wv_h Wo_h)[c][d]           : 968
#define WS_W1T   2296   // W1T[f][c]    = W1[c][f]                    : 2816
#define WS_WRES  5112   // W_res'[c] = g_ff[c]*W_res[c]               : 22
#define WS_BRES  5134   // [0]=b_res + b_ff@W_res, [1]=sum(W_res')    : 2
// total 5136 floats = 20544 bytes

__global__ void setup_k(const float* __restrict__ W_rel, const float* __restrict__ b_rel,
                        const float* __restrict__ Wq, const float* __restrict__ Wk,
                        const float* __restrict__ Wv, const float* __restrict__ Wo,
                        const float* __restrict__ W1, const float* __restrict__ Wp,
                        const float* __restrict__ bp, const float* __restrict__ g_ff,
                        const float* __restrict__ b_ff, const float* __restrict__ W_res,
                        const float* __restrict__ b_res, float* __restrict__ ws)
{
    const int t = threadIdx.x;
    for (int idx = t; idx < 198; idx += 256) {
        int l = idx / 22, d = idx % 22, tt = d / 2;
        float div = __expf((float)(2 * tt) * (-logf(10000.f) / 22.f));
        float ang = (float)l * div;
        ws[WS_PE + idx] = (d & 1) ? cosf(ang) : sinf(ang);
    }
    for (int idx = t; idx < 162; idx += 256) {
        int h = idx / 81, rem = idx % 81, i = rem / 9, j = rem % 9;
        float s = bp[h];
        for (int d = 0; d < 22; ++d)
            s += (W_rel[(i - j + 9) * 22 + d] + b_rel[d]) * Wp[d * 2 + h];
        ws[WS_PB + idx] = s;
    }
    for (int idx = t; idx < 968; idx += 256) {
        int h = idx / 484, rem = idx % 484, cp = rem / 22, c = rem % 22;
        float s = 0.f;
        for (int e = 0; e < 22; ++e)
            s += Wq[c * 44 + h * 22 + e] * Wk[cp * 44 + h * 22 + e];
        ws[WS_MT + idx] = s * 0.21320071635561041f; // 1/sqrt(22)
    }
    for (int idx = t; idx < 968; idx += 256) {
        int h = idx / 484, rem = idx % 484, d = rem / 22, c = rem % 22;
        float s = 0.f;
        for (int e = 0; e < 22; ++e)
            s += Wv[c * 44 + h * 22 + e] * Wo[(h * 22 + e) * 22 + d];
        ws[WS_VWO + idx] = s;
    }
    for (int idx = t; idx < 2816; idx += 256) {
        int f = idx / 22, c = idx % 22;
        ws[WS_W1T + idx] = W1[c * 128 + f];
    }
    // folded residue head: W_res' = g_ff .* W_res ; b_res' = b_res + b_ff@W_res ; SW = sum(W_res')
    if (t < 22) ws[WS_WRES + t] = g_ff[t] * W_res[t];
    if (t == 0) {
        float br = b_res[0], sw = 0.f;
        for (int c = 0; c < 22; ++c) {
            br += b_ff[c] * W_res[c];
            sw += g_ff[c] * W_res[c];
        }
        ws[WS_BRES + 0] = br;
        ws[WS_BRES + 1] = sw;
    }
}

// VGPR discipline (empirical, rounds 1-5): must land in (64,128] for the
// 16-waves/CU occupancy step. min-waves=2 caps the allocator at 128 regs
// (hipcc budgets min-waves against a 256-reg pool: 5->48, 4->64, 2->128);
// att[] merged into x[] keeps natural pressure ~120 so the cap doesn't spill.
__global__ __launch_bounds__(TPB, 2) void fused_model(
    const float* __restrict__ seq, const float* __restrict__ ws,
    const float* __restrict__ g_att, const float* __restrict__ b_att,
    const float* __restrict__ b1, const float* __restrict__ W2,
    const float* __restrict__ b2, const float* __restrict__ W_out,
    const float* __restrict__ b_out, float* __restrict__ out)
{
    // x rows (padded to 24); x stays valid through the whole attention phase.
    __shared__ __align__(16) float xbuf[RPB][L_][24];   // 24192 B

    const int tid = threadIdx.x;
    const int r = tid / L_;
    const int i = tid - r * L_;
    const long g = (long)blockIdx.x * RPB + r;
    const bool active = g < B_TOT;
    const long gc = active ? g : (long)(B_TOT - 1);

    // ---- prefetch attention bias into the score accumulators ----
    float p0[L_], p1[L_];
    {
        const float* pb = ws + WS_PB + i * L_;
        #pragma unroll
        for (int j = 0; j < L_; ++j) p0[j] = pb[j];
        #pragma unroll
        for (int j = 0; j < L_; ++j) p1[j] = pb[81 + j];
    }

    // ---- load x = seq_embd + pe ----
    float x[D_];
    {
        const float* xin = seq + gc * (L_ * D_) + i * D_;
        const float* pe  = ws + WS_PE + i * D_;
        #pragma unroll
        for (int c = 0; c < D_; c += 2) {
            float2 t = *reinterpret_cast<const float2*>(xin + c);
            x[c]     = t.x + pe[c];
            x[c + 1] = t.y + pe[c + 1];
        }
    }
    {
        float4* row = reinterpret_cast<float4*>(&xbuf[r][i][0]);
        row[0] = make_float4(x[0], x[1], x[2], x[3]);
        row[1] = make_float4(x[4], x[5], x[6], x[7]);
        row[2] = make_float4(x[8], x[9], x[10], x[11]);
        row[3] = make_float4(x[12], x[13], x[14], x[15]);
        row[4] = make_float4(x[16], x[17], x[18], x[19]);
        row[5] = make_float4(x[20], x[21], 0.f, 0.f);
    }
    __syncthreads();   // the ONLY data barrier in the attention phase

    // ---- scores for BOTH heads (x register copy still pristine) ----
    #pragma unroll
    for (int h = 0; h < H_; ++h) {
        const float* MT = ws + WS_MT + h * (D_ * D_);
        float qm[D_];
        #pragma unroll
        for (int d = 0; d < D_; ++d) {
            float s = 0.f;
            #pragma unroll
            for (int c = 0; c < D_; ++c) s += x[c] * MT[d * D_ + c];
            qm[d] = s;
        }
        float* p = h ? p1 : p0;
        #pragma unroll
        for (int j = 0; j < L_; ++j) {
            const float4* xr = reinterpret_cast<const float4*>(&xbuf[r][j][0]);
            float4 a0 = xr[0], a1 = xr[1], a2 = xr[2], a3 = xr[3], a4 = xr[4];
            float2 a5 = *reinterpret_cast<const float2*>(&xbuf[r][j][20]);
            float s = p[j];
            s += qm[0]*a0.x + qm[1]*a0.y + qm[2]*a0.z + qm[3]*a0.w;
            s += qm[4]*a1.x + qm[5]*a1.y + qm[6]*a1.z + qm[7]*a1.w;
            s += qm[8]*a2.x + qm[9]*a2.y + qm[10]*a2.z + qm[11]*a2.w;
            s += qm[12]*a3.x + qm[13]*a3.y + qm[14]*a3.z + qm[15]*a3.w;
            s += qm[16]*a4.x + qm[17]*a4.y + qm[18]*a4.z + qm[19]*a4.w;
            s += qm[20]*a5.x + qm[21]*a5.y;
            p[j] = s;
        }
    }

    // ---- softmax both heads, in registers (pre-normalized) ----
    {
        float mx = -1e30f;
        #pragma unroll
        for (int j = 0; j < L_; ++j) mx = fmaxf(mx, p0[j]);
        float sum = 0.f;
        #pragma unroll
        for (int j = 0; j < L_; ++j) { p0[j] = __expf(p0[j] - mx); sum += p0[j]; }
        const float inv = 1.f / sum;
        #pragma unroll
        for (int j = 0; j < L_; ++j) p0[j] *= inv;
    }
    {
        float mx = -1e30f;
        #pragma unroll
        for (int j = 0; j < L_; ++j) mx = fmaxf(mx, p1[j]);
        float sum = 0.f;
        #pragma unroll
        for (int j = 0; j < L_; ++j) { p1[j] = __expf(p1[j] - mx); sum += p1[j]; }
        const float inv = 1.f / sum;
        #pragma unroll
        for (int j = 0; j < L_; ++j) p1[j] *= inv;
    }

    // ---- PV: x += sum_h (sum_j p_hj x_j) @ Wvo_h
    //      (attention output accumulated straight into the residual — no att[]) ----
    #pragma unroll
    for (int h = 0; h < H_; ++h) {
        const float* WVOT = ws + WS_VWO + h * (D_ * D_);
        const float* p = h ? p1 : p0;
        float ctx[D_];
        #pragma unroll
        for (int c = 0; c < D_; ++c) ctx[c] = 0.f;
        #pragma unroll
        for (int j = 0; j < L_; ++j) {
            const float4* xr = reinterpret_cast<const float4*>(&xbuf[r][j][0]);
            float4 a0 = xr[0], a1 = xr[1], a2 = xr[2], a3 = xr[3], a4 = xr[4];
            float2 a5 = *reinterpret_cast<const float2*>(&xbuf[r][j][20]);
            const float pj = p[j];
            ctx[0]  += pj * a0.x; ctx[1]  += pj * a0.y; ctx[2]  += pj * a0.z; ctx[3]  += pj * a0.w;
            ctx[4]  += pj * a1.x; ctx[5]  += pj * a1.y; ctx[6]  += pj * a1.z; ctx[7]  += pj * a1.w;
            ctx[8]  += pj * a2.x; ctx[9]  += pj * a2.y; ctx[10] += pj * a2.z; ctx[11] += pj * a2.w;
            ctx[12] += pj * a3.x; ctx[13] += pj * a3.y; ctx[14] += pj * a3.z; ctx[15] += pj * a3.w;
            ctx[16] += pj * a4.x; ctx[17] += pj * a4.y; ctx[18] += pj * a4.z; ctx[19] += pj * a4.w;
            ctx[20] += pj * a5.x; ctx[21] += pj * a5.y;
        }
        #pragma unroll
        for (int d = 0; d < D_; ++d) {
            float s = 0.f;
            #pragma unroll
            for (int c = 0; c < D_; ++c) s += ctx[c] * WVOT[d * D_ + c];
            x[d] += s;
        }
    }

    // ---- LayerNorm 1 (residual already in x) ----
    {
        float s = 0.f;
        #pragma unroll
        for (int c = 0; c < D_; ++c) s += x[c];
        const float mean = s * (1.f / 22.f);
        float vs = 0.f;
        #pragma unroll
        for (int c = 0; c < D_; ++c) { float d = x[c] - mean; vs += d * d; }
        const float rstd = rsqrtf(vs * (1.f / 22.f) + 1e-5f);
        #pragma unroll
        for (int c = 0; c < D_; ++c) x[c] = (x[c] - mean) * rstd * g_att[c] + b_att[c];
    }

    // ---- feed-forward (residual into x) ----
    {
        float y2[D_];
        #pragma unroll
        for (int c = 0; c < D_; ++c) y2[c] = b2[c];
        const float* W1T = ws + WS_W1T;
        #pragma unroll 4
        for (int f = 0; f < FF_; ++f) {
            float s = b1[f];
            #pragma unroll
            for (int c = 0; c < D_; ++c) s += x[c] * W1T[f * D_ + c];
            s = fmaxf(s, 0.f);
            #pragma unroll
            for (int c = 0; c < D_; ++c) y2[c] += s * W2[f * D_ + c];
        }
        #pragma unroll
        for (int c = 0; c < D_; ++c) x[c] += y2[c];
    }

    // ---- LN2 + residue head, fully folded:
    //      pr = b_res' + rstd * (dot(t, W_res') - mean * sum(W_res'))   ----
    float pr;
    {
        float s = 0.f;
        #pragma unroll
        for (int c = 0; c < D_; ++c) s += x[c];
        const float mean = s * (1.f / 22.f);
        float vs = 0.f;
        #pragma unroll
        for (int c = 0; c < D_; ++c) { float d = x[c] - mean; vs += d * d; }
        const float rstd = rsqrtf(vs * (1.f / 22.f) + 1e-5f);
        const float* wr = ws + WS_WRES;
        float dot = 0.f;
        #pragma unroll
        for (int c = 0; c < D_; ++c) dot += x[c] * wr[c];
        pr = ws[WS_BRES + 0] + rstd * (dot - mean * ws[WS_BRES + 1]);
    }

    // ---- output head (reduce over L via LDS overlay) ----
    float* red = reinterpret_cast<float*>(xbuf);   // overlay: [tid*2 + {0,1}]
    __syncthreads();   // all xbuf reads done before overlay write
    red[tid * 2 + 0] = pr * W_out[i * 2 + 0];
    red[tid * 2 + 1] = pr * W_out[i * 2 + 1];
    __syncthreads();
    if (i == 0 && active) {
        float o0 = b_out[0], o1 = b_out[1];
        #pragma unroll
        for (int j = 0; j < L_; ++j) {
            o0 += red[(r * L_ + j) * 2 + 0];
            o1 += red[(r * L_ + j) * 2 + 1];
        }
        float2 o; o.x = o0; o.y = o1;
        *reinterpret_cast<float2*>(out + g * 2) = o;
    }
}

extern "C" void kernel_launch(void* const* d_in, const int* in_sizes, int n_in,
                              void* d_out, int out_size, void* d_ws, size_t ws_size,
                              hipStream_t stream)
{
    const float* seq   = (const float*)d_in[0];
    const float* W_rel = (const float*)d_in[1];
    const float* b_rel = (const float*)d_in[2];
    const float* Wq    = (const float*)d_in[3];
    const float* Wk    = (const float*)d_in[4];
    const float* Wv    = (const float*)d_in[5];
    const float* Wo    = (const float*)d_in[6];
    const float* g_att = (const float*)d_in[7];
    const float* b_att = (const float*)d_in[8];
    const float* W1    = (const float*)d_in[9];
    const float* b1    = (const float*)d_in[10];
    const float* W2    = (const float*)d_in[11];
    const float* b2    = (const float*)d_in[12];
    const float* Wp    = (const float*)d_in[13];
    const float* bp    = (const float*)d_in[14];
    const float* g_ff  = (const float*)d_in[15];
    const float* b_ff  = (const float*)d_in[16];
    const float* W_res = (const float*)d_in[17];
    const float* b_res = (const float*)d_in[18];
    const float* W_out = (const float*)d_in[19];
    const float* b_out = (const float*)d_in[20];
    float* out = (float*)d_out;
    float* ws  = (float*)d_ws;

    setup_k<<<1, 256, 0, stream>>>(W_rel, b_rel, Wq, Wk, Wv, Wo, W1, Wp, bp,
                                   g_ff, b_ff, W_res, b_res, ws);

    const int grid = (B_TOT + RPB - 1) / RPB;
    fused_model<<<grid, TPB, 0, stream>>>(seq, ws, g_att, b_att, b1, W2, b2,
                                          W_out, b_out, out);
}

// Round 10
// 504.066 us; speedup vs baseline: 2.1059x; 1.7370x over previous
//
#include <hip/hip_runtime.h>

#define B_TOT 131072
#define L_ 9
#define D_ 22
#define H_ 2
#define FF_ 128
#define RPB 28            // rows per block
#define TPB (RPB * L_)    // 252 threads

// ---- workspace layout (floats) ----
#define WS_PE    0      // pe[9][22]                                  : 198
#define WS_PB    198    // pbias[h][i][j]                             : 162
#define WS_MT    360    // MT[h][d][c]  = (Wq_h Wk_h^T/sqrt22)[c][d]  : 968
#define WS_VWO   1328   // WVOT[h][d][c]= (Wv_h Wo_h)[c][d]           : 968
#define WS_W1T   2296   // W1T[f][c]    = W1[c][f]                    : 2816
#define WS_WRES  5112   // W_res'[c] = g_ff[c]*W_res[c]               : 22
#define WS_BRES  5134   // [0]=b_res + b_ff@W_res, [1]=sum(W_res')    : 2
// total 5136 floats = 20544 bytes

__global__ void setup_k(const float* __restrict__ W_rel, const float* __restrict__ b_rel,
                        const float* __restrict__ Wq, const float* __restrict__ Wk,
                        const float* __restrict__ Wv, const float* __restrict__ Wo,
                        const float* __restrict__ W1, const float* __restrict__ Wp,
                        const float* __restrict__ bp, const float* __restrict__ g_ff,
                        const float* __restrict__ b_ff, const float* __restrict__ W_res,
                        const float* __restrict__ b_res, float* __restrict__ ws)
{
    const int t = threadIdx.x;
    for (int idx = t; idx < 198; idx += 256) {
        int l = idx / 22, d = idx % 22, tt = d / 2;
        float div = __expf((float)(2 * tt) * (-logf(10000.f) / 22.f));
        float ang = (float)l * div;
        ws[WS_PE + idx] = (d & 1) ? cosf(ang) : sinf(ang);
    }
    for (int idx = t; idx < 162; idx += 256) {
        int h = idx / 81, rem = idx % 81, i = rem / 9, j = rem % 9;
        float s = bp[h];
        for (int d = 0; d < 22; ++d)
            s += (W_rel[(i - j + 9) * 22 + d] + b_rel[d]) * Wp[d * 2 + h];
        ws[WS_PB + idx] = s;
    }
    for (int idx = t; idx < 968; idx += 256) {
        int h = idx / 484, rem = idx % 484, cp = rem / 22, c = rem % 22;
        float s = 0.f;
        for (int e = 0; e < 22; ++e)
            s += Wq[c * 44 + h * 22 + e] * Wk[cp * 44 + h * 22 + e];
        ws[WS_MT + idx] = s * 0.21320071635561041f; // 1/sqrt(22)
    }
    for (int idx = t; idx < 968; idx += 256) {
        int h = idx / 484, rem = idx % 484, d = rem / 22, c = rem % 22;
        float s = 0.f;
        for (int e = 0; e < 22; ++e)
            s += Wv[c * 44 + h * 22 + e] * Wo[(h * 22 + e) * 22 + d];
        ws[WS_VWO + idx] = s;
    }
    for (int idx = t; idx < 2816; idx += 256) {
        int f = idx / 22, c = idx % 22;
        ws[WS_W1T + idx] = W1[c * 128 + f];
    }
    // folded residue head: W_res' = g_ff .* W_res ; b_res' = b_res + b_ff@W_res ; SW = sum(W_res')
    if (t < 22) ws[WS_WRES + t] = g_ff[t] * W_res[t];
    if (t == 0) {
        float br = b_res[0], sw = 0.f;
        for (int c = 0; c < 22; ++c) {
            br += b_ff[c] * W_res[c];
            sw += g_ff[c] * W_res[c];
        }
        ws[WS_BRES + 0] = br;
        ws[WS_BRES + 1] = sw;
    }
}

// VGPR discipline (rounds 1-7): target (64,128] for the 16-waves/CU step.
// min-waves=2 caps the allocator at 128 (hipcc budgets vs a 256-reg pool:
// 5->48, 4->64, 2->128). Round 7 showed natural pressure 148 = the fully
// unrolled j-loops keeping 9 rows x 22 floats of LDS data in flight; the
// `#pragma unroll 1` on every attention j-loop bounds that to one row, so
// pressure lands ~115 and the cap no longer spills.
__global__ __launch_bounds__(TPB, 2) void fused_model(
    const float* __restrict__ seq, const float* __restrict__ ws,
    const float* __restrict__ g_att, const float* __restrict__ b_att,
    const float* __restrict__ b1, const float* __restrict__ W2,
    const float* __restrict__ b2, const float* __restrict__ W_out,
    const float* __restrict__ b_out, float* __restrict__ out)
{
    __shared__ __align__(16) float xbuf[RPB][L_][24];   // 24192 B

    const int tid = threadIdx.x;
    const int r = tid / L_;
    const int i = tid - r * L_;
    const long g = (long)blockIdx.x * RPB + r;
    const bool active = g < B_TOT;
    const long gc = active ? g : (long)(B_TOT - 1);

    // ---- prefetch attention bias into the score accumulators ----
    float p0[L_], p1[L_];
    {
        const float* pb = ws + WS_PB + i * L_;
        #pragma unroll
        for (int j = 0; j < L_; ++j) p0[j] = pb[j];
        #pragma unroll
        for (int j = 0; j < L_; ++j) p1[j] = pb[81 + j];
    }

    // ---- load x = seq_embd + pe ----
    float x[D_];
    {
        const float* xin = seq + gc * (L_ * D_) + i * D_;
        const float* pe  = ws + WS_PE + i * D_;
        #pragma unroll
        for (int c = 0; c < D_; c += 2) {
            float2 t = *reinterpret_cast<const float2*>(xin + c);
            x[c]     = t.x + pe[c];
            x[c + 1] = t.y + pe[c + 1];
        }
    }
    {
        float4* row = reinterpret_cast<float4*>(&xbuf[r][i][0]);
        row[0] = make_float4(x[0], x[1], x[2], x[3]);
        row[1] = make_float4(x[4], x[5], x[6], x[7]);
        row[2] = make_float4(x[8], x[9], x[10], x[11]);
        row[3] = make_float4(x[12], x[13], x[14], x[15]);
        row[4] = make_float4(x[16], x[17], x[18], x[19]);
        row[5] = make_float4(x[20], x[21], 0.f, 0.f);
    }
    __syncthreads();   // the ONLY data barrier in the attention phase

    // ---- qm for BOTH heads, then ONE score pass over j ----
    {
        float qm0[D_], qm1[D_];
        #pragma unroll
        for (int d = 0; d < D_; ++d) {
            const float* m0 = ws + WS_MT + d * D_;
            float s = 0.f;
            #pragma unroll
            for (int c = 0; c < D_; ++c) s += x[c] * m0[c];
            qm0[d] = s;
        }
        #pragma unroll
        for (int d = 0; d < D_; ++d) {
            const float* m1 = ws + WS_MT + 484 + d * D_;
            float s = 0.f;
            #pragma unroll
            for (int c = 0; c < D_; ++c) s += x[c] * m1[c];
            qm1[d] = s;
        }
        #pragma unroll 1
        for (int j = 0; j < L_; ++j) {
            const float4* xr = reinterpret_cast<const float4*>(&xbuf[r][j][0]);
            float4 a0 = xr[0], a1 = xr[1], a2 = xr[2], a3 = xr[3], a4 = xr[4];
            float2 a5 = *reinterpret_cast<const float2*>(&xbuf[r][j][20]);
            float s0 = qm0[0]*a0.x + qm0[1]*a0.y + qm0[2]*a0.z + qm0[3]*a0.w
                     + qm0[4]*a1.x + qm0[5]*a1.y + qm0[6]*a1.z + qm0[7]*a1.w
                     + qm0[8]*a2.x + qm0[9]*a2.y + qm0[10]*a2.z + qm0[11]*a2.w
                     + qm0[12]*a3.x + qm0[13]*a3.y + qm0[14]*a3.z + qm0[15]*a3.w
                     + qm0[16]*a4.x + qm0[17]*a4.y + qm0[18]*a4.z + qm0[19]*a4.w
                     + qm0[20]*a5.x + qm0[21]*a5.y;
            float s1 = qm1[0]*a0.x + qm1[1]*a0.y + qm1[2]*a0.z + qm1[3]*a0.w
                     + qm1[4]*a1.x + qm1[5]*a1.y + qm1[6]*a1.z + qm1[7]*a1.w
                     + qm1[8]*a2.x + qm1[9]*a2.y + qm1[10]*a2.z + qm1[11]*a2.w
                     + qm1[12]*a3.x + qm1[13]*a3.y + qm1[14]*a3.z + qm1[15]*a3.w
                     + qm1[16]*a4.x + qm1[17]*a4.y + qm1[18]*a4.z + qm1[19]*a4.w
                     + qm1[20]*a5.x + qm1[21]*a5.y;
            p0[j] += s0;
            p1[j] += s1;
        }
    }

    // ---- softmax both heads, in registers (pre-normalized) ----
    {
        float mx = -1e30f;
        #pragma unroll
        for (int j = 0; j < L_; ++j) mx = fmaxf(mx, p0[j]);
        float sum = 0.f;
        #pragma unroll
        for (int j = 0; j < L_; ++j) { p0[j] = __expf(p0[j] - mx); sum += p0[j]; }
        const float inv = 1.f / sum;
        #pragma unroll
        for (int j = 0; j < L_; ++j) p0[j] *= inv;
    }
    {
        float mx = -1e30f;
        #pragma unroll
        for (int j = 0; j < L_; ++j) mx = fmaxf(mx, p1[j]);
        float sum = 0.f;
        #pragma unroll
        for (int j = 0; j < L_; ++j) { p1[j] = __expf(p1[j] - mx); sum += p1[j]; }
        const float inv = 1.f / sum;
        #pragma unroll
        for (int j = 0; j < L_; ++j) p1[j] *= inv;
    }

    // ---- PV per head: ctx = sum_j p_j x_j, then x += ctx @ Wvo_h ----
    #pragma unroll
    for (int h = 0; h < H_; ++h) {
        const float* WVOT = ws + WS_VWO + h * (D_ * D_);
        const float* p = h ? p1 : p0;
        float ctx[D_];
        #pragma unroll
        for (int c = 0; c < D_; ++c) ctx[c] = 0.f;
        #pragma unroll 1
        for (int j = 0; j < L_; ++j) {
            const float4* xr = reinterpret_cast<const float4*>(&xbuf[r][j][0]);
            float4 a0 = xr[0], a1 = xr[1], a2 = xr[2], a3 = xr[3], a4 = xr[4];
            float2 a5 = *reinterpret_cast<const float2*>(&xbuf[r][j][20]);
            const float pj = p[j];
            ctx[0]  += pj * a0.x; ctx[1]  += pj * a0.y; ctx[2]  += pj * a0.z; ctx[3]  += pj * a0.w;
            ctx[4]  += pj * a1.x; ctx[5]  += pj * a1.y; ctx[6]  += pj * a1.z; ctx[7]  += pj * a1.w;
            ctx[8]  += pj * a2.x; ctx[9]  += pj * a2.y; ctx[10] += pj * a2.z; ctx[11] += pj * a2.w;
            ctx[12] += pj * a3.x; ctx[13] += pj * a3.y; ctx[14] += pj * a3.z; ctx[15] += pj * a3.w;
            ctx[16] += pj * a4.x; ctx[17] += pj * a4.y; ctx[18] += pj * a4.z; ctx[19] += pj * a4.w;
            ctx[20] += pj * a5.x; ctx[21] += pj * a5.y;
        }
        #pragma unroll
        for (int d = 0; d < D_; ++d) {
            const float* w = WVOT + d * D_;
            float s = 0.f;
            #pragma unroll
            for (int c = 0; c < D_; ++c) s += ctx[c] * w[c];
            x[d] += s;
        }
    }

    // ---- LayerNorm 1 (residual already in x) ----
    {
        float s = 0.f;
        #pragma unroll
        for (int c = 0; c < D_; ++c) s += x[c];
        const float mean = s * (1.f / 22.f);
        float vs = 0.f;
        #pragma unroll
        for (int c = 0; c < D_; ++c) { float d = x[c] - mean; vs += d * d; }
        const float rstd = rsqrtf(vs * (1.f / 22.f) + 1e-5f);
        #pragma unroll
        for (int c = 0; c < D_; ++c) x[c] = (x[c] - mean) * rstd * g_att[c] + b_att[c];
    }

    // ---- feed-forward (residual into x) ----
    {
        float y2[D_];
        #pragma unroll
        for (int c = 0; c < D_; ++c) y2[c] = b2[c];
        const float* W1T = ws + WS_W1T;
        #pragma unroll 4
        for (int f = 0; f < FF_; ++f) {
            float s = b1[f];
            #pragma unroll
            for (int c = 0; c < D_; ++c) s += x[c] * W1T[f * D_ + c];
            s = fmaxf(s, 0.f);
            #pragma unroll
            for (int c = 0; c < D_; ++c) y2[c] += s * W2[f * D_ + c];
        }
        #pragma unroll
        for (int c = 0; c < D_; ++c) x[c] += y2[c];
    }

    // ---- LN2 + residue head, fully folded ----
    float pr;
    {
        float s = 0.f;
        #pragma unroll
        for (int c = 0; c < D_; ++c) s += x[c];
        const float mean = s * (1.f / 22.f);
        float vs = 0.f;
        #pragma unroll
        for (int c = 0; c < D_; ++c) { float d = x[c] - mean; vs += d * d; }
        const float rstd = rsqrtf(vs * (1.f / 22.f) + 1e-5f);
        const float* wr = ws + WS_WRES;
        float dot = 0.f;
        #pragma unroll
        for (int c = 0; c < D_; ++c) dot += x[c] * wr[c];
        pr = ws[WS_BRES + 0] + rstd * (dot - mean * ws[WS_BRES + 1]);
    }

    // ---- output head (reduce over L via LDS overlay) ----
    float* red = reinterpret_cast<float*>(xbuf);   // overlay: [tid*2 + {0,1}]
    __syncthreads();   // all xbuf reads done before overlay write
    red[tid * 2 + 0] = pr * W_out[i * 2 + 0];
    red[tid * 2 + 1] = pr * W_out[i * 2 + 1];
    __syncthreads();
    if (i == 0 && active) {
        float o0 = b_out[0], o1 = b_out[1];
        #pragma unroll
        for (int j = 0; j < L_; ++j) {
            o0 += red[(r * L_ + j) * 2 + 0];
            o1 += red[(r * L_ + j) * 2 + 1];
        }
        float2 o; o.x = o0; o.y = o1;
        *reinterpret_cast<float2*>(out + g * 2) = o;
    }
}

extern "C" void kernel_launch(void* const* d_in, const int* in_sizes, int n_in,
                              void* d_out, int out_size, void* d_ws, size_t ws_size,
                              hipStream_t stream)
{
    const float* seq   = (const float*)d_in[0];
    const float* W_rel = (const float*)d_in[1];
    const float* b_rel = (const float*)d_in[2];
    const float* Wq    = (const float*)d_in[3];
    const float* Wk    = (const float*)d_in[4];
    const float* Wv    = (const float*)d_in[5];
    const float* Wo    = (const float*)d_in[6];
    const float* g_att = (const float*)d_in[7];
    const float* b_att = (const float*)d_in[8];
    const float* W1    = (const float*)d_in[9];
    const float* b1    = (const float*)d_in[10];
    const float* W2    = (const float*)d_in[11];
    const float* b2    = (const float*)d_in[12];
    const float* Wp    = (const float*)d_in[13];
    const float* bp    = (const float*)d_in[14];
    const float* g_ff  = (const float*)d_in[15];
    const float* b_ff  = (const float*)d_in[16];
    const float* W_res = (const float*)d_in[17];
    const float* b_res = (const float*)d_in[18];
    const float* W_out = (const float*)d_in[19];
    const float* b_out = (const float*)d_in[20];
    float* out = (float*)d_out;
    float* ws  = (float*)d_ws;

    setup_k<<<1, 256, 0, stream>>>(W_rel, b_rel, Wq, Wk, Wv, Wo, W1, Wp, bp,
                                   g_ff, b_ff, W_res, b_res, ws);

    const int grid = (B_TOT + RPB - 1) / RPB;
    fused_model<<<grid, TPB, 0, stream>>>(seq, ws, g_att, b_att, b1, W2, b2,
                                          W_out, b_out, out);
}